// Round 11
// baseline (740.748 us; speedup 1.0000x reference)
//
#include <hip/hip_runtime.h>

// GCN 3-layer: N=50000, E=1.6M, D_IN=256, H=128, D_OUT=64, fp32 in/out.
// R12: bucketed counting sort killed the global-atomic wall.
// R13-R19: fused SpMM+GEMM ladder ended at sg=68.8us; R19 A/B proved the
//   gather is NOT VMEM-inst-rate limited -> pattern ceiling: every XCD
//   randomly touches all 12.8MB of T, thrashing its 4MiB L2 (FETCH 157MB).
// R20/R21: XCD FEATURE-SHARDING. aggf block handles 16-feature (32B) slice
//   (bid%8) of 32 nodes (bid/8). Round-robin block->XCD dispatch => XCD k
//   only touches slice k => 3.2MB line working set, L2-RESIDENT: random
//   gather becomes an L2 hit. col re-read 8x via nontemporal loads (don't
//   evict T); Hf stores nontemporal (via clang ext_vector_type -- R20's
//   HIP float2 fails the builtin's type check). Cost: GEMM un-fused ->
//   standalone gemm_mfma (R2-proven) + Hf fp32 round-trip. Correct under
//   ANY block->XCD mapping; fast under round-robin.
// Pipeline: initprep -> bin -> scan -> fusedA2[gemm1|scatter] -> csr(+scaleT)
//   -> aggf -> gemm<128,128> -> aggf -> gemm<128,64> -> spmm64 = 10 launches.
// Requires n <= 65536 (16-bit packing; harness n = 50000).

constexpr int DIN = 256;
constexpr int HID = 128;
constexpr int DOUT = 64;
constexpr int MAXB = 1024;   // max buckets (n <= 65536)
constexpr int BSH = 6;       // 64 nodes per bucket
constexpr int EPB = 8192;    // edges per bin/scatter block

typedef unsigned short ushort_t;
typedef unsigned int uint_t;
typedef __attribute__((ext_vector_type(8))) short bf16x8;
typedef __attribute__((ext_vector_type(4))) float f32x4;
typedef __attribute__((ext_vector_type(2))) float f32x2;  // clang vector: ok for nontemporal builtins

__device__ inline ushort_t f2bf(float f) {
  uint_t u = __float_as_uint(f);
  u += 0x7FFF + ((u >> 16) & 1);  // RNE
  return (ushort_t)(u >> 16);
}
__device__ inline float bf2f(ushort_t b) {
  return __uint_as_float(((uint_t)b) << 16);
}

// 32-bit-offset gather loads: uniform base + (c<<SH | lane_bytes) voffset.
// SH = log2(row bytes). Lets the compiler emit global_load saddr form.
template <int SH>
__device__ inline uint_t ldrow32(const ushort_t* __restrict__ t, int c, uint_t lb) {
  return *(const uint_t*)((const char*)t + ((((uint_t)c) << SH) | lb));
}

// ---------- weight prep (device fn): W[K][F] fp32 -> fragment bf16 hi/lo ----------
// Layout: Bp[t = n/16][s = k/32][lane = (k/8 % 4)*16 + n%16][j = k%8]

__device__ inline void wprep_one(const float* __restrict__ W, ushort_t* __restrict__ Bhi,
                                 ushort_t* __restrict__ Blo, int K, int F, int i) {
  int k = i / F, nn = i % F;
  int t = nn >> 4, s = k >> 5, q = (k >> 3) & 3, j = k & 7;
  int lane = q * 16 + (nn & 15);
  int KS = K >> 5;
  size_t idx = (((size_t)t * KS + s) * 64 + (size_t)lane) * 8 + j;
  float w = W[i];
  ushort_t h = f2bf(w);
  float r = w - bf2f(h);
  Bhi[idx] = h;
  Blo[idx] = f2bf(r);
}

// ---------- init: zero bucket_total + wprep x3 ----------

__global__ __launch_bounds__(256) void initprep_kernel(
    int* __restrict__ bucket_total, int iblocks,
    const float* __restrict__ W1, ushort_t* __restrict__ W1hi, ushort_t* __restrict__ W1lo,
    const float* __restrict__ W2, ushort_t* __restrict__ W2hi, ushort_t* __restrict__ W2lo,
    const float* __restrict__ W3, ushort_t* __restrict__ W3hi, ushort_t* __restrict__ W3lo) {
  if ((int)blockIdx.x < iblocks) {
    int i = blockIdx.x * 256 + threadIdx.x;
    if (i < MAXB) bucket_total[i] = 0;
  } else {
    int idx = ((int)blockIdx.x - iblocks) * 256 + threadIdx.x;
    constexpr int S1 = DIN * HID;        // 32768
    constexpr int S2 = S1 + HID * HID;   // 49152
    constexpr int S3 = S2 + HID * DOUT;  // 57344
    if (idx < S1) wprep_one(W1, W1hi, W1lo, DIN, HID, idx);
    else if (idx < S2) wprep_one(W2, W2hi, W2lo, HID, HID, idx - S1);
    else if (idx < S3) wprep_one(W3, W3hi, W3lo, HID, DOUT, idx - S2);
  }
}

// ---------- bin pass: per-block LDS histogram over buckets ----------
// One returning global atomic per (block,bucket) -> block's base within bucket.

__global__ __launch_bounds__(256) void bin_kernel(const int* __restrict__ dst, int e,
    int nbuckets, int* __restrict__ bucket_total, int* __restrict__ block_base) {
  __shared__ int h[MAXB];
  int tid = threadIdx.x;
  for (int i = tid; i < nbuckets; i += 256) h[i] = 0;
  __syncthreads();
  int base = blockIdx.x * EPB;
  int end = min(base + EPB, e);
  for (int i = base + tid; i < end; i += 256) atomicAdd(&h[dst[i] >> BSH], 1);
  __syncthreads();
  for (int i = tid; i < nbuckets; i += 256) {
    int v = h[i];
    if (v) block_base[(size_t)blockIdx.x * nbuckets + i] = atomicAdd(&bucket_total[i], v);
  }
}

// ---------- bucket scan: exclusive scan of bucket_total (+ sentinel) ----------

__global__ __launch_bounds__(256) void scan_buckets_kernel(const int* __restrict__ total,
    int* __restrict__ base, int nb) {
  __shared__ int sums[256];
  int t = threadIdx.x;
  int a[4];
  int ls = 0;
#pragma unroll
  for (int k = 0; k < 4; ++k) {
    int idx = t * 4 + k;
    a[k] = (idx < nb) ? total[idx] : 0;
    ls += a[k];
  }
  sums[t] = ls;
  __syncthreads();
  for (int off = 1; off < 256; off <<= 1) {
    int u = (t >= off) ? sums[t - off] : 0;
    __syncthreads();
    sums[t] += u;
    __syncthreads();
  }
  int run = sums[t] - ls;  // exclusive
#pragma unroll
  for (int k = 0; k < 4; ++k) {
    int idx = t * 4 + k;
    if (idx < nb) base[idx] = run;
    run += a[k];
  }
  if (t == 255) base[nb] = sums[255];  // sentinel = e
}

// ---------- split-bf16 MFMA GEMM (device fn) ----------
// 256 threads = 4 waves; 64 rows per block-id; wave w: rows +16w..+16w+15.
// acc = Ahi*Bhi + Alo*Bhi + Ahi*Blo (fp32 accum; lo*lo dropped, ~2^-18 rel).

template <int K, int F, bool SCALE>
__device__ inline void gemm_mfma_dev(const float* __restrict__ X,
    const ushort_t* __restrict__ Bhi, const ushort_t* __restrict__ Blo,
    const float* __restrict__ dinv, ushort_t* __restrict__ T, int n, int bid) {
  constexpr int NT = F / 16;   // n-tiles
  constexpr int KS = K / 32;   // k-steps
  int wave = threadIdx.x >> 6;
  int lane = threadIdx.x & 63;
  int q = lane >> 4;
  int m = lane & 15;
  int arow = bid * 64 + wave * 16 + m;
  bool valid = arow < n;
  const float* xrow = X + (size_t)arow * K;

  f32x4 acc[NT];
#pragma unroll
  for (int t = 0; t < NT; ++t) acc[t] = (f32x4){0.f, 0.f, 0.f, 0.f};

  for (int s = 0; s < KS; ++s) {
    float av[8];
    if (valid) {
      float4 u0 = *(const float4*)(xrow + s * 32 + q * 8);
      float4 u1 = *(const float4*)(xrow + s * 32 + q * 8 + 4);
      av[0] = u0.x; av[1] = u0.y; av[2] = u0.z; av[3] = u0.w;
      av[4] = u1.x; av[5] = u1.y; av[6] = u1.z; av[7] = u1.w;
    } else {
#pragma unroll
      for (int j = 0; j < 8; ++j) av[j] = 0.f;
    }
    bf16x8 ahi, alo;
#pragma unroll
    for (int j = 0; j < 8; ++j) {
      ushort_t h = f2bf(av[j]);
      ahi[j] = (short)h;
      alo[j] = (short)f2bf(av[j] - bf2f(h));
    }
#pragma unroll
    for (int t = 0; t < NT; ++t) {
      size_t boff = (((size_t)t * KS + s) * 64 + (size_t)lane) * 8;
      bf16x8 bh = *(const bf16x8*)(Bhi + boff);
      bf16x8 bl = *(const bf16x8*)(Blo + boff);
      acc[t] = __builtin_amdgcn_mfma_f32_16x16x32_bf16(ahi, bh, acc[t], 0, 0, 0);
      acc[t] = __builtin_amdgcn_mfma_f32_16x16x32_bf16(alo, bh, acc[t], 0, 0, 0);
      acc[t] = __builtin_amdgcn_mfma_f32_16x16x32_bf16(ahi, bl, acc[t], 0, 0, 0);
    }
  }

  int orow_base = bid * 64 + wave * 16 + q * 4;
#pragma unroll
  for (int r = 0; r < 4; ++r) {
    int orow = orow_base + r;
    if (orow >= n) continue;
    float sc = SCALE ? dinv[orow] : 1.0f;
    ushort_t* trow = T + (size_t)orow * F + m;
#pragma unroll
    for (int t = 0; t < NT; ++t) trow[t * 16] = f2bf(sc * acc[t][r]);
  }
}

template <int K, int F>
__global__ __launch_bounds__(256) void gemm_mfma_kernel(const float* __restrict__ X,
    const ushort_t* __restrict__ Bhi, const ushort_t* __restrict__ Blo,
    const float* __restrict__ dinv, ushort_t* __restrict__ T, int n) {
  gemm_mfma_dev<K, F, true>(X, Bhi, Blo, dinv, T, n, blockIdx.x);
}

// ---------- fused A2: [gemm1 unscaled | scatter into buckets] ----------
// scatter: LDS re-histogram gives rank within (block,bucket); position =
// bucket_base[b] + block_base[blk][b] + rank. Zero global atomics.

__global__ __launch_bounds__(256) void fusedA2_kernel(
    const float* __restrict__ X, const ushort_t* __restrict__ Bhi,
    const ushort_t* __restrict__ Blo, ushort_t* __restrict__ T, int n, int gblocks,
    const int* __restrict__ src, const int* __restrict__ dst,
    const int* __restrict__ bucket_base, const int* __restrict__ block_base,
    uint_t* __restrict__ binned, int e, int nbuckets) {
  if ((int)blockIdx.x < gblocks) {
    gemm_mfma_dev<DIN, HID, false>(X, Bhi, Blo, nullptr, T, n, blockIdx.x);
  } else {
    __shared__ int rkh[MAXB];
    __shared__ int cbase[MAXB];
    int tid = threadIdx.x;
    int blk = (int)blockIdx.x - gblocks;
    for (int i = tid; i < nbuckets; i += 256) {
      rkh[i] = 0;
      cbase[i] = bucket_base[i] + block_base[(size_t)blk * nbuckets + i];
    }
    __syncthreads();
    int base = blk * EPB;
    int end = min(base + EPB, e);
    for (int i = base + tid; i < end; i += 256) {
      int d = dst[i];
      int s = src[i];
      int b = d >> BSH;
      int r = atomicAdd(&rkh[b], 1);
      binned[cbase[b] + r] = ((uint_t)d << 16) | (uint_t)s;
    }
  }
}

// ---------- per-bucket CSR build + Ta pre-scale ----------
// Bucket = contiguous node range -> offsets are bucket-local; no global scan.
// Also scales this bucket's 64 Ta rows by dinv[row] in place (bf16) so the
// downstream gathers need NO per-edge dinv loads.

__global__ __launch_bounds__(256) void csr_kernel(const uint_t* __restrict__ binned,
    const int* __restrict__ bucket_base, int n, int* __restrict__ row_start,
    int* __restrict__ deg, float* __restrict__ dinv, int* __restrict__ col,
    ushort_t* __restrict__ Ta) {
  __shared__ int cnt[64];
  __shared__ int rk[64];
  __shared__ int rs[64];
  __shared__ float sdinv[64];
  __shared__ int ebs[2];
  int tid = threadIdx.x;
  int b = blockIdx.x;
  int node0 = b << BSH;
  if (tid < 64) { cnt[tid] = 0; rk[tid] = 0; }
  if (tid == 0) { ebs[0] = bucket_base[b]; ebs[1] = bucket_base[b + 1]; }
  __syncthreads();
  int ebase = ebs[0];
  int esz = ebs[1] - ebase;
  for (int i = tid; i < esz; i += 256)
    atomicAdd(&cnt[(int)(binned[ebase + i] >> 16) - node0], 1);
  __syncthreads();
  if (tid < 64) {
    int v = cnt[tid];
    int inc = v;
#pragma unroll
    for (int off = 1; off < 64; off <<= 1) {
      int u = __shfl_up(inc, off, 64);
      if (tid >= off) inc += u;
    }
    rs[tid] = inc - v;  // exclusive within bucket
    float di = rsqrtf((float)(v + 1));
    sdinv[tid] = di;
    int node = node0 + tid;
    if (node < n) {
      deg[node] = v + 1;                      // + self-loop
      dinv[node] = di;
      row_start[node] = ebase + (inc - v);
    }
  }
  __syncthreads();
  for (int i = tid; i < esz; i += 256) {
    uint_t p = binned[ebase + i];
    int l = (int)(p >> 16) - node0;
    int r = atomicAdd(&rk[l], 1);
    col[ebase + rs[l] + r] = (int)(p & 0xFFFFu);
  }
  // ---- scale Ta rows (bf16 in place): 64 rows x 16 uint4 each ----
  int nrows = min(64, n - node0);
  if (nrows > 0) {
    uint4* tw = (uint4*)Ta + ((size_t)node0 << 4);  // 16 uint4 per row
    int nv4 = nrows << 4;
    for (int i = tid; i < nv4; i += 256) {
      float sc = sdinv[i >> 4];
      uint4 w = tw[i];
      uint_t ww[4] = {w.x, w.y, w.z, w.w};
#pragma unroll
      for (int j = 0; j < 4; ++j) {
        float lo = sc * bf2f((ushort_t)(ww[j] & 0xFFFF));
        float hi = sc * bf2f((ushort_t)(ww[j] >> 16));
        ww[j] = (uint_t)f2bf(lo) | ((uint_t)f2bf(hi) << 16);
      }
      w.x = ww[0]; w.y = ww[1]; w.z = ww[2]; w.w = ww[3];
      tw[i] = w;
    }
  }
}

// ---------- feature-sliced SpMM aggregate (inner layers) ----------
// Block = (slice = bid & 7, group = bid >> 3): 16-feature (32B) slice of
// 32 nodes. Round-robin block->XCD dispatch => XCD k only touches slice k
// of T: line working set = n x 64B = 3.2MB, L2-RESIDENT. 8 lanes per node
// (1 uint = 2 bf16 features per lane), batch-8 edge loop = 64 row-slices
// in flight per wave. col via nontemporal loads, Hf via nontemporal stores
// (keep L2 for T). Rows pre-scaled by dinv -> pure adds.
// Hf[node] = relu(dinv[node] * (T[node] + sum_c T[c]) + bias), fp32.

__global__ __launch_bounds__(256) void aggf_kernel(
    const ushort_t* __restrict__ t, const int* __restrict__ row_start,
    const int* __restrict__ deg, const int* __restrict__ col,
    const float* __restrict__ dinv, const float* __restrict__ bias,
    float* __restrict__ Hf, int n) {
  constexpr int NPB = 32;
  int bid = (int)blockIdx.x;
  int slice = bid & 7;
  int grp = (int)threadIdx.x >> 3;      // node within block (0..31)
  int u = threadIdx.x & 7;              // uint within 32B slice
  int node = (bid >> 3) * NPB + grp;
  bool hv = node < n;
  int vnode = hv ? node : 0;
  int rs = row_start[vnode];
  int e  = hv ? deg[vnode] - 1 : 0;
  float di = hv ? dinv[vnode] : 0.f;
  uint_t lb = ((uint_t)slice << 5) | ((uint_t)u << 2);

  uint_t sv = ldrow32<8>(t, vnode, lb);
  float a0 = bf2f((ushort_t)(sv & 0xFFFF));
  float a1 = bf2f((ushort_t)(sv >> 16));

  for (int k = 0; k < e; k += 8) {
    int c[8];
    uint_t v[8];
#pragma unroll
    for (int j = 0; j < 8; ++j)
      c[j] = __builtin_nontemporal_load(col + ((k + j) < e ? (rs + k + j) : rs));
#pragma unroll
    for (int j = 0; j < 8; ++j) v[j] = ldrow32<8>(t, c[j], lb);
#pragma unroll
    for (int j = 0; j < 8; ++j) {
      if ((k + j) < e) {
        a0 += bf2f((ushort_t)(v[j] & 0xFFFF));
        a1 += bf2f((ushort_t)(v[j] >> 16));
      }
    }
  }
  if (hv) {
    int f0 = slice * 16 + 2 * u;
    f32x2 o;
    o.x = fmaxf(fmaf(di, a0, bias[f0]), 0.f);
    o.y = fmaxf(fmaf(di, a1, bias[f0 + 1]), 0.f);
    __builtin_nontemporal_store(o, (f32x2*)(Hf + (size_t)node * HID + f0));
  }
}

// ---------- final CSR SpMM, half-wave layout ----------
// F=64 rows (128 B). Lanes 0-31 own node n0, lanes 32-63 own n1: each gather
// is a uint (4 B/lane, full row per half-wave). Per-half own-e loop, batch-8.

__global__ __launch_bounds__(256) void spmm64_kernel(const ushort_t* __restrict__ t,
    const int* __restrict__ row_start, const int* __restrict__ deg,
    const int* __restrict__ col, const float* __restrict__ dinv,
    const float* __restrict__ bias, float* __restrict__ out, int n) {
  int gw = (int)((blockIdx.x * 256u + threadIdx.x) >> 6);
  int lane = threadIdx.x & 63;
  int half = lane >> 5;
  int hl = lane & 31;
  int n0 = gw * 2;
  if (n0 >= n) return;
  int node = n0 + half;
  bool valid = node < n;
  int vnode = valid ? node : n0;
  int rs = row_start[vnode];
  int e  = valid ? (deg[vnode] - 1) : 0;
  float di = dinv[vnode];
  uint_t lb = (uint_t)hl << 2;

  uint_t su = ldrow32<7>(t, vnode, lb);
  float ax = bf2f((ushort_t)(su & 0xFFFF));
  float ay = bf2f((ushort_t)(su >> 16));

  for (int k = 0; k < e; k += 8) {
    int c[8];
    uint_t v[8];
#pragma unroll
    for (int j = 0; j < 8; ++j) c[j] = col[(k + j) < e ? (rs + k + j) : rs];
#pragma unroll
    for (int j = 0; j < 8; ++j) v[j] = ldrow32<7>(t, c[j], lb);
#pragma unroll
    for (int j = 0; j < 8; ++j) {
      if ((k + j) < e) {
        ax += bf2f((ushort_t)(v[j] & 0xFFFF));
        ay += bf2f((ushort_t)(v[j] >> 16));
      }
    }
  }
  if (valid) {
    float bx = bias[2 * hl], by = bias[2 * hl + 1];
    ax = fmaf(di, ax, bx);
    ay = fmaf(di, ay, by);
    float2 o;
    o.x = ax;
    o.y = ay;
    *(float2*)(out + (size_t)node * DOUT + 2 * hl) = o;
  }
}

// ---------- launch ----------

extern "C" void kernel_launch(void* const* d_in, const int* in_sizes, int n_in,
                              void* d_out, int out_size, void* d_ws, size_t ws_size,
                              hipStream_t stream) {
  const float* x  = (const float*)d_in[0];
  const float* W1 = (const float*)d_in[1];
  const float* b1 = (const float*)d_in[2];
  const float* W2 = (const float*)d_in[3];
  const float* b2 = (const float*)d_in[4];
  const float* W3 = (const float*)d_in[5];
  const float* b3 = (const float*)d_in[6];
  const int* ei   = (const int*)d_in[7];  // harness delivers integers as int32

  int n = in_sizes[0] / DIN;
  int e = in_sizes[7] / 2;
  const int* src = ei;
  const int* dst = ei + e;

  char* ws = (char*)d_ws;
  size_t off = 0;
  auto alloc = [&](size_t bytes) -> void* {
    off = (off + 255) & ~(size_t)255;
    void* p = ws + off;
    off += bytes;
    return p;
  };
  int nbuckets = (n + 63) >> BSH;          // <= MAXB for n <= 65536
  int nbin = (e + EPB - 1) / EPB;

  int*      bucket_total = (int*)alloc((size_t)MAXB * 4);
  int*      bucket_base  = (int*)alloc((size_t)(MAXB + 1) * 4);
  int*      block_base   = (int*)alloc((size_t)nbin * nbuckets * 4);
  uint_t*   binned       = (uint_t*)alloc((size_t)e * 4);
  int*      deg          = (int*)alloc((size_t)n * 4);
  float*    dinv         = (float*)alloc((size_t)n * 4);
  int*      row_start    = (int*)alloc((size_t)n * 4);
  int*      col          = (int*)alloc((size_t)e * 4);
  ushort_t* Ta           = (ushort_t*)alloc((size_t)n * HID * 2);  // bf16 rows
  ushort_t* Tb           = (ushort_t*)alloc((size_t)n * HID * 2);  // bf16 rows
  float*    Hf           = (float*)alloc((size_t)n * HID * 4);     // fp32 agg out
  ushort_t* W1hi         = (ushort_t*)alloc((size_t)DIN * HID * 2);
  ushort_t* W1lo         = (ushort_t*)alloc((size_t)DIN * HID * 2);
  ushort_t* W2hi         = (ushort_t*)alloc((size_t)HID * HID * 2);
  ushort_t* W2lo         = (ushort_t*)alloc((size_t)HID * HID * 2);
  ushort_t* W3hi         = (ushort_t*)alloc((size_t)HID * DOUT * 2);
  ushort_t* W3lo         = (ushort_t*)alloc((size_t)HID * DOUT * 2);
  (void)ws_size;

  int gemm_blocks = (n + 63) / 64;
  int agg_groups = (n + 31) / 32;           // 32 nodes per group
  int agg_blocks = agg_groups * 8;          // x8 feature slices
  int nwaves = (n + 1) / 2;                 // 2 nodes per wave (final spmm)
  int spmm_blocks = (nwaves + 3) / 4;       // 4 waves per block
  constexpr int WPREP_TOTAL = DIN * HID + HID * HID + HID * DOUT;  // 57344
  int wblocks = (WPREP_TOTAL + 255) / 256;  // 224
  int iblocks = MAXB / 256;                 // 4

  initprep_kernel<<<iblocks + wblocks, 256, 0, stream>>>(
      bucket_total, iblocks,
      W1, W1hi, W1lo, W2, W2hi, W2lo, W3, W3hi, W3lo);
  bin_kernel<<<nbin, 256, 0, stream>>>(dst, e, nbuckets, bucket_total, block_base);
  scan_buckets_kernel<<<1, 256, 0, stream>>>(bucket_total, bucket_base, nbuckets);
  fusedA2_kernel<<<gemm_blocks + nbin, 256, 0, stream>>>(
      x, W1hi, W1lo, Ta, n, gemm_blocks,
      src, dst, bucket_base, block_base, binned, e, nbuckets);
  csr_kernel<<<nbuckets, 256, 0, stream>>>(binned, bucket_base, n, row_start,
                                           deg, dinv, col, Ta);

  // layer 1 aggregate (feature-sliced, L2-resident): Ta -> Hf (fp32, relu'd)
  aggf_kernel<<<agg_blocks, 256, 0, stream>>>(
      Ta, row_start, deg, col, dinv, b1, Hf, n);
  // layer 2 GEMM: Tb = dinv * (Hf @ W2), bf16
  gemm_mfma_kernel<HID, HID><<<gemm_blocks, 256, 0, stream>>>(
      Hf, W2hi, W2lo, dinv, Tb, n);
  // layer 2 aggregate: Tb -> Hf
  aggf_kernel<<<agg_blocks, 256, 0, stream>>>(
      Tb, row_start, deg, col, dinv, b2, Hf, n);
  // layer 3 GEMM: Ta = dinv * (Hf @ W3), bf16 (n x 64)
  gemm_mfma_kernel<HID, DOUT><<<gemm_blocks, 256, 0, stream>>>(
      Hf, W3hi, W3lo, dinv, Ta, n);
  // layer 3 aggregate (final): Ta -> out (fp32) + b3
  spmm64_kernel<<<spmm_blocks, 256, 0, stream>>>(
      Ta, row_start, deg, col, dinv, b3, (float*)d_out, n);
}

// Round 12
// 330.662 us; speedup vs baseline: 2.2402x; 2.2402x over previous
//
#include <hip/hip_runtime.h>

// GCN 3-layer: N=50000, E=1.6M, D_IN=256, H=128, D_OUT=64, fp32 in/out.
// R12: bucketed counting sort killed the global-atomic wall (~17G/s ceiling).
// R13-R18: fused SpMM+GEMM (16 nodes/block, 512 thr, full MFMA tile), saddr
//   gathers, batch-8, csr-fused Ta pre-scale, half-wave spmm64.
// R19: half-wave dwordx2 gathers (1 VMEM inst = 2 rows) -- NEUTRAL, proving
//   the gather is at the random-access pattern ceiling, not inst-rate bound.
// R20/21: XCD feature-sharding FAILED (L2 fill granule 128B >> 32B slice:
//   4x overfetch + still-thrashing 6.4MB/XCD working set; FETCH 157->554MB).
//   Lesson: sub-line sharding is impossible; >=128B slices give only 2 shards
//   = still over L2. REVERT to R19 (best verified: 330us).
// Terminal state: inner-layer gather (2x ~68us) is at the measured fabric
//   ceiling for L2-nonresident random 256B-row gathers (~2.4-3.2 TB/s,
//   invariant under MLP, inst-rate, occupancy, and locality restructurings).
// Pipeline: initprep -> bin -> scan -> fusedA2[gemm1|scatter] -> csr(+scaleT)
//   -> spmm_gemm<128> -> spmm_gemm<64> -> spmm64 = 8 launches.
// Requires n <= 65536 (16-bit packing; harness n = 50000).

constexpr int DIN = 256;
constexpr int HID = 128;
constexpr int DOUT = 64;
constexpr int MAXB = 1024;   // max buckets (n <= 65536)
constexpr int BSH = 6;       // 64 nodes per bucket
constexpr int EPB = 8192;    // edges per bin/scatter block

typedef unsigned short ushort_t;
typedef unsigned int uint_t;
typedef __attribute__((ext_vector_type(8))) short bf16x8;
typedef __attribute__((ext_vector_type(4))) float f32x4;

__device__ inline ushort_t f2bf(float f) {
  uint_t u = __float_as_uint(f);
  u += 0x7FFF + ((u >> 16) & 1);  // RNE
  return (ushort_t)(u >> 16);
}
__device__ inline float bf2f(ushort_t b) {
  return __uint_as_float(((uint_t)b) << 16);
}

// 32-bit-offset gather loads: uniform base + (c<<SH | lane_bytes) voffset.
// SH = log2(row bytes). Lets the compiler emit global_load saddr form.
template <int SH>
__device__ inline uint_t ldrow32(const ushort_t* __restrict__ t, int c, uint_t lb) {
  return *(const uint_t*)((const char*)t + ((((uint_t)c) << SH) | lb));
}
template <int SH>
__device__ inline uint2 ldrow64(const ushort_t* __restrict__ t, int c, uint_t lb) {
  return *(const uint2*)((const char*)t + ((((uint_t)c) << SH) | lb));
}

// ---------- weight prep (device fn): W[K][F] fp32 -> fragment bf16 hi/lo ----------
// Layout: Bp[t = n/16][s = k/32][lane = (k/8 % 4)*16 + n%16][j = k%8]

__device__ inline void wprep_one(const float* __restrict__ W, ushort_t* __restrict__ Bhi,
                                 ushort_t* __restrict__ Blo, int K, int F, int i) {
  int k = i / F, nn = i % F;
  int t = nn >> 4, s = k >> 5, q = (k >> 3) & 3, j = k & 7;
  int lane = q * 16 + (nn & 15);
  int KS = K >> 5;
  size_t idx = (((size_t)t * KS + s) * 64 + (size_t)lane) * 8 + j;
  float w = W[i];
  ushort_t h = f2bf(w);
  float r = w - bf2f(h);
  Bhi[idx] = h;
  Blo[idx] = f2bf(r);
}

// ---------- init: zero bucket_total + wprep x3 ----------

__global__ __launch_bounds__(256) void initprep_kernel(
    int* __restrict__ bucket_total, int iblocks,
    const float* __restrict__ W1, ushort_t* __restrict__ W1hi, ushort_t* __restrict__ W1lo,
    const float* __restrict__ W2, ushort_t* __restrict__ W2hi, ushort_t* __restrict__ W2lo,
    const float* __restrict__ W3, ushort_t* __restrict__ W3hi, ushort_t* __restrict__ W3lo) {
  if ((int)blockIdx.x < iblocks) {
    int i = blockIdx.x * 256 + threadIdx.x;
    if (i < MAXB) bucket_total[i] = 0;
  } else {
    int idx = ((int)blockIdx.x - iblocks) * 256 + threadIdx.x;
    constexpr int S1 = DIN * HID;        // 32768
    constexpr int S2 = S1 + HID * HID;   // 49152
    constexpr int S3 = S2 + HID * DOUT;  // 57344
    if (idx < S1) wprep_one(W1, W1hi, W1lo, DIN, HID, idx);
    else if (idx < S2) wprep_one(W2, W2hi, W2lo, HID, HID, idx - S1);
    else if (idx < S3) wprep_one(W3, W3hi, W3lo, HID, DOUT, idx - S2);
  }
}

// ---------- bin pass: per-block LDS histogram over buckets ----------
// One returning global atomic per (block,bucket) -> block's base within bucket.

__global__ __launch_bounds__(256) void bin_kernel(const int* __restrict__ dst, int e,
    int nbuckets, int* __restrict__ bucket_total, int* __restrict__ block_base) {
  __shared__ int h[MAXB];
  int tid = threadIdx.x;
  for (int i = tid; i < nbuckets; i += 256) h[i] = 0;
  __syncthreads();
  int base = blockIdx.x * EPB;
  int end = min(base + EPB, e);
  for (int i = base + tid; i < end; i += 256) atomicAdd(&h[dst[i] >> BSH], 1);
  __syncthreads();
  for (int i = tid; i < nbuckets; i += 256) {
    int v = h[i];
    if (v) block_base[(size_t)blockIdx.x * nbuckets + i] = atomicAdd(&bucket_total[i], v);
  }
}

// ---------- bucket scan: exclusive scan of bucket_total (+ sentinel) ----------

__global__ __launch_bounds__(256) void scan_buckets_kernel(const int* __restrict__ total,
    int* __restrict__ base, int nb) {
  __shared__ int sums[256];
  int t = threadIdx.x;
  int a[4];
  int ls = 0;
#pragma unroll
  for (int k = 0; k < 4; ++k) {
    int idx = t * 4 + k;
    a[k] = (idx < nb) ? total[idx] : 0;
    ls += a[k];
  }
  sums[t] = ls;
  __syncthreads();
  for (int off = 1; off < 256; off <<= 1) {
    int u = (t >= off) ? sums[t - off] : 0;
    __syncthreads();
    sums[t] += u;
    __syncthreads();
  }
  int run = sums[t] - ls;  // exclusive
#pragma unroll
  for (int k = 0; k < 4; ++k) {
    int idx = t * 4 + k;
    if (idx < nb) base[idx] = run;
    run += a[k];
  }
  if (t == 255) base[nb] = sums[255];  // sentinel = e
}

// ---------- split-bf16 MFMA GEMM (device fn) ----------
// 256 threads = 4 waves; 64 rows per block-id; wave w: rows +16w..+16w+15.
// acc = Ahi*Bhi + Alo*Bhi + Ahi*Blo (fp32 accum; lo*lo dropped, ~2^-18 rel).

template <int K, int F, bool SCALE>
__device__ inline void gemm_mfma_dev(const float* __restrict__ X,
    const ushort_t* __restrict__ Bhi, const ushort_t* __restrict__ Blo,
    const float* __restrict__ dinv, ushort_t* __restrict__ T, int n, int bid) {
  constexpr int NT = F / 16;   // n-tiles
  constexpr int KS = K / 32;   // k-steps
  int wave = threadIdx.x >> 6;
  int lane = threadIdx.x & 63;
  int q = lane >> 4;
  int m = lane & 15;
  int arow = bid * 64 + wave * 16 + m;
  bool valid = arow < n;
  const float* xrow = X + (size_t)arow * K;

  f32x4 acc[NT];
#pragma unroll
  for (int t = 0; t < NT; ++t) acc[t] = (f32x4){0.f, 0.f, 0.f, 0.f};

  for (int s = 0; s < KS; ++s) {
    float av[8];
    if (valid) {
      float4 u0 = *(const float4*)(xrow + s * 32 + q * 8);
      float4 u1 = *(const float4*)(xrow + s * 32 + q * 8 + 4);
      av[0] = u0.x; av[1] = u0.y; av[2] = u0.z; av[3] = u0.w;
      av[4] = u1.x; av[5] = u1.y; av[6] = u1.z; av[7] = u1.w;
    } else {
#pragma unroll
      for (int j = 0; j < 8; ++j) av[j] = 0.f;
    }
    bf16x8 ahi, alo;
#pragma unroll
    for (int j = 0; j < 8; ++j) {
      ushort_t h = f2bf(av[j]);
      ahi[j] = (short)h;
      alo[j] = (short)f2bf(av[j] - bf2f(h));
    }
#pragma unroll
    for (int t = 0; t < NT; ++t) {
      size_t boff = (((size_t)t * KS + s) * 64 + (size_t)lane) * 8;
      bf16x8 bh = *(const bf16x8*)(Bhi + boff);
      bf16x8 bl = *(const bf16x8*)(Blo + boff);
      acc[t] = __builtin_amdgcn_mfma_f32_16x16x32_bf16(ahi, bh, acc[t], 0, 0, 0);
      acc[t] = __builtin_amdgcn_mfma_f32_16x16x32_bf16(alo, bh, acc[t], 0, 0, 0);
      acc[t] = __builtin_amdgcn_mfma_f32_16x16x32_bf16(ahi, bl, acc[t], 0, 0, 0);
    }
  }

  int orow_base = bid * 64 + wave * 16 + q * 4;
#pragma unroll
  for (int r = 0; r < 4; ++r) {
    int orow = orow_base + r;
    if (orow >= n) continue;
    float sc = SCALE ? dinv[orow] : 1.0f;
    ushort_t* trow = T + (size_t)orow * F + m;
#pragma unroll
    for (int t = 0; t < NT; ++t) trow[t * 16] = f2bf(sc * acc[t][r]);
  }
}

// ---------- fused A2: [gemm1 unscaled | scatter into buckets] ----------
// scatter: LDS re-histogram gives rank within (block,bucket); position =
// bucket_base[b] + block_base[blk][b] + rank. Zero global atomics.

__global__ __launch_bounds__(256) void fusedA2_kernel(
    const float* __restrict__ X, const ushort_t* __restrict__ Bhi,
    const ushort_t* __restrict__ Blo, ushort_t* __restrict__ T, int n, int gblocks,
    const int* __restrict__ src, const int* __restrict__ dst,
    const int* __restrict__ bucket_base, const int* __restrict__ block_base,
    uint_t* __restrict__ binned, int e, int nbuckets) {
  if ((int)blockIdx.x < gblocks) {
    gemm_mfma_dev<DIN, HID, false>(X, Bhi, Blo, nullptr, T, n, blockIdx.x);
  } else {
    __shared__ int rkh[MAXB];
    __shared__ int cbase[MAXB];
    int tid = threadIdx.x;
    int blk = (int)blockIdx.x - gblocks;
    for (int i = tid; i < nbuckets; i += 256) {
      rkh[i] = 0;
      cbase[i] = bucket_base[i] + block_base[(size_t)blk * nbuckets + i];
    }
    __syncthreads();
    int base = blk * EPB;
    int end = min(base + EPB, e);
    for (int i = base + tid; i < end; i += 256) {
      int d = dst[i];
      int s = src[i];
      int b = d >> BSH;
      int r = atomicAdd(&rkh[b], 1);
      binned[cbase[b] + r] = ((uint_t)d << 16) | (uint_t)s;
    }
  }
}

// ---------- per-bucket CSR build + Ta pre-scale ----------
// Bucket = contiguous node range -> offsets are bucket-local; no global scan.
// Also scales this bucket's 64 Ta rows by dinv[row] in place (bf16) so the
// downstream sg1 gather needs NO per-edge dinv loads.

__global__ __launch_bounds__(256) void csr_kernel(const uint_t* __restrict__ binned,
    const int* __restrict__ bucket_base, int n, int* __restrict__ row_start,
    int* __restrict__ deg, float* __restrict__ dinv, int* __restrict__ col,
    ushort_t* __restrict__ Ta) {
  __shared__ int cnt[64];
  __shared__ int rk[64];
  __shared__ int rs[64];
  __shared__ float sdinv[64];
  __shared__ int ebs[2];
  int tid = threadIdx.x;
  int b = blockIdx.x;
  int node0 = b << BSH;
  if (tid < 64) { cnt[tid] = 0; rk[tid] = 0; }
  if (tid == 0) { ebs[0] = bucket_base[b]; ebs[1] = bucket_base[b + 1]; }
  __syncthreads();
  int ebase = ebs[0];
  int esz = ebs[1] - ebase;
  for (int i = tid; i < esz; i += 256)
    atomicAdd(&cnt[(int)(binned[ebase + i] >> 16) - node0], 1);
  __syncthreads();
  if (tid < 64) {
    int v = cnt[tid];
    int inc = v;
#pragma unroll
    for (int off = 1; off < 64; off <<= 1) {
      int u = __shfl_up(inc, off, 64);
      if (tid >= off) inc += u;
    }
    rs[tid] = inc - v;  // exclusive within bucket
    float di = rsqrtf((float)(v + 1));
    sdinv[tid] = di;
    int node = node0 + tid;
    if (node < n) {
      deg[node] = v + 1;                      // + self-loop
      dinv[node] = di;
      row_start[node] = ebase + (inc - v);
    }
  }
  __syncthreads();
  for (int i = tid; i < esz; i += 256) {
    uint_t p = binned[ebase + i];
    int l = (int)(p >> 16) - node0;
    int r = atomicAdd(&rk[l], 1);
    col[ebase + rs[l] + r] = (int)(p & 0xFFFFu);
  }
  // ---- scale Ta rows (bf16 in place): 64 rows x 16 uint4 each ----
  int nrows = min(64, n - node0);
  if (nrows > 0) {
    uint4* tw = (uint4*)Ta + ((size_t)node0 << 4);  // 16 uint4 per row
    int nv4 = nrows << 4;
    for (int i = tid; i < nv4; i += 256) {
      float sc = sdinv[i >> 4];
      uint4 w = tw[i];
      uint_t ww[4] = {w.x, w.y, w.z, w.w};
#pragma unroll
      for (int j = 0; j < 4; ++j) {
        float lo = sc * bf2f((ushort_t)(ww[j] & 0xFFFF));
        float hi = sc * bf2f((ushort_t)(ww[j] >> 16));
        ww[j] = (uint_t)f2bf(lo) | ((uint_t)f2bf(hi) << 16);
      }
      w.x = ww[0]; w.y = ww[1]; w.z = ww[2]; w.w = ww[3];
      tw[i] = w;
    }
  }
}

// ---------- fused SpMM + GEMM (inner layers), 16 nodes/block, 8 waves ----------
// Phase 1: half-wave node ownership -- lanes 0-31 own node A, 32-63 node B;
//          dwordx2 gathers (8B/lane, features 4hl..4hl+3): ONE VMEM inst reads
//          TWO 256B rows. Batch-8 predicated loop = 16 rows in flight/wave.
//          Rows pre-scaled by dinv -> pure adds.
// Phase 2: FULL 16-row x 128 @ 128xFOUT MFMA. FOUT=128: 8 waves x 1 tile;
//          FOUT=64: waves 0-3 compute, 4-7 retire after barrier.

template <int FOUT>
__global__ __launch_bounds__(512) void spmm_gemm_kernel(
    const ushort_t* __restrict__ t, const int* __restrict__ row_start,
    const int* __restrict__ deg, const int* __restrict__ col,
    const float* __restrict__ dinv, const float* __restrict__ bias,
    const ushort_t* __restrict__ Bhi, const ushort_t* __restrict__ Blo,
    ushort_t* __restrict__ Tout, int n) {
  constexpr int FIN = 128;      // row = 256 B -> shift 8
  constexpr int NPB = 16;       // nodes per block
  constexpr int LDW = FIN + 4;  // LDS row stride (floats; 528B = 33*16 aligned)
  __shared__ float agg[NPB][LDW];
  int wave = threadIdx.x >> 6;  // 0..7
  int lane = threadIdx.x & 63;
  int nb0 = (int)blockIdx.x * NPB;

  // ---- phase 1: gather-aggregate (half-wave node ownership) ----
  {
    int half = lane >> 5;
    int hl = lane & 31;
    int ln = wave * 2 + half;       // LDS row this half fills
    int node = nb0 + ln;
    bool hv = node < n;
    int vnode = hv ? node : 0;
    int rs = row_start[vnode];
    int e  = hv ? (deg[vnode] - 1) : 0;
    float di = hv ? dinv[vnode] : 0.f;
    uint_t lb = (uint_t)hl << 3;    // 8B granule: features 4hl..4hl+3

    float a0 = 0.f, a1 = 0.f, a2 = 0.f, a3 = 0.f;
    {
      uint2 s = ldrow64<8>(t, vnode, lb);
      a0 = bf2f((ushort_t)(s.x & 0xFFFF)); a1 = bf2f((ushort_t)(s.x >> 16));
      a2 = bf2f((ushort_t)(s.y & 0xFFFF)); a3 = bf2f((ushort_t)(s.y >> 16));
      if (!hv) { a0 = a1 = a2 = a3 = 0.f; }
    }
    int emax = max(e, __shfl_xor(e, 32));
    for (int k = 0; k < emax; k += 8) {
      int c[8];
      uint2 v[8];
#pragma unroll
      for (int j = 0; j < 8; ++j) c[j] = col[(k + j) < e ? (rs + k + j) : rs];
#pragma unroll
      for (int j = 0; j < 8; ++j) v[j] = ldrow64<8>(t, c[j], lb);
#pragma unroll
      for (int j = 0; j < 8; ++j) {
        if ((k + j) < e) {
          a0 += bf2f((ushort_t)(v[j].x & 0xFFFF));
          a1 += bf2f((ushort_t)(v[j].x >> 16));
          a2 += bf2f((ushort_t)(v[j].y & 0xFFFF));
          a3 += bf2f((ushort_t)(v[j].y >> 16));
        }
      }
    }
    float4 bb = *(const float4*)(bias + 4 * hl);
    float4 o;
    o.x = hv ? fmaxf(fmaf(di, a0, bb.x), 0.f) : 0.f;
    o.y = hv ? fmaxf(fmaf(di, a1, bb.y), 0.f) : 0.f;
    o.z = hv ? fmaxf(fmaf(di, a2, bb.z), 0.f) : 0.f;
    o.w = hv ? fmaxf(fmaf(di, a3, bb.w), 0.f) : 0.f;
    *(float4*)&agg[ln][4 * hl] = o;
  }
  __syncthreads();

  // ---- phase 2: FULL 16-row x 128 @ 128 x FOUT MFMA ----
  constexpr int NT = FOUT / 16;  // 8 (FOUT=128) or 4 (FOUT=64)
  constexpr int KS = FIN / 32;
  if (wave < NT) {
    int q = lane >> 4, m = lane & 15;
    f32x4 acc = (f32x4){0.f, 0.f, 0.f, 0.f};
    const float* arow = &agg[m][0];
#pragma unroll
    for (int s = 0; s < KS; ++s) {
      float4 u0 = *(const float4*)(arow + s * 32 + q * 8);
      float4 u1 = *(const float4*)(arow + s * 32 + q * 8 + 4);
      float av[8];
      av[0] = u0.x; av[1] = u0.y; av[2] = u0.z; av[3] = u0.w;
      av[4] = u1.x; av[5] = u1.y; av[6] = u1.z; av[7] = u1.w;
      bf16x8 ahi, alo;
#pragma unroll
      for (int j = 0; j < 8; ++j) {
        ushort_t h = f2bf(av[j]);
        ahi[j] = (short)h;
        alo[j] = (short)f2bf(av[j] - bf2f(h));
      }
      size_t boff = (((size_t)wave * KS + s) * 64 + (size_t)lane) * 8;
      bf16x8 bh = *(const bf16x8*)(Bhi + boff);
      bf16x8 bl = *(const bf16x8*)(Blo + boff);
      acc = __builtin_amdgcn_mfma_f32_16x16x32_bf16(ahi, bh, acc, 0, 0, 0);
      acc = __builtin_amdgcn_mfma_f32_16x16x32_bf16(alo, bh, acc, 0, 0, 0);
      acc = __builtin_amdgcn_mfma_f32_16x16x32_bf16(ahi, bl, acc, 0, 0, 0);
    }
#pragma unroll
    for (int r = 0; r < 4; ++r) {
      int orow = nb0 + q * 4 + r;
      if (orow >= n) continue;
      float sc = dinv[orow];
      Tout[(size_t)orow * FOUT + wave * 16 + m] = f2bf(sc * acc[r]);
    }
  }
}

// ---------- final CSR SpMM, half-wave layout ----------
// F=64 rows (128 B). Lanes 0-31 own node n0, lanes 32-63 own n1: each gather
// is a uint (4 B/lane, full row per half-wave). Per-half own-e loop, batch-8.

__global__ __launch_bounds__(256) void spmm64_kernel(const ushort_t* __restrict__ t,
    const int* __restrict__ row_start, const int* __restrict__ deg,
    const int* __restrict__ col, const float* __restrict__ dinv,
    const float* __restrict__ bias, float* __restrict__ out, int n) {
  int gw = (int)((blockIdx.x * 256u + threadIdx.x) >> 6);
  int lane = threadIdx.x & 63;
  int half = lane >> 5;
  int hl = lane & 31;
  int n0 = gw * 2;
  if (n0 >= n) return;
  int node = n0 + half;
  bool valid = node < n;
  int vnode = valid ? node : n0;
  int rs = row_start[vnode];
  int e  = valid ? (deg[vnode] - 1) : 0;
  float di = dinv[vnode];
  uint_t lb = (uint_t)hl << 2;

  uint_t su = ldrow32<7>(t, vnode, lb);
  float ax = bf2f((ushort_t)(su & 0xFFFF));
  float ay = bf2f((ushort_t)(su >> 16));

  for (int k = 0; k < e; k += 8) {
    int c[8];
    uint_t v[8];
#pragma unroll
    for (int j = 0; j < 8; ++j) c[j] = col[(k + j) < e ? (rs + k + j) : rs];
#pragma unroll
    for (int j = 0; j < 8; ++j) v[j] = ldrow32<7>(t, c[j], lb);
#pragma unroll
    for (int j = 0; j < 8; ++j) {
      if ((k + j) < e) {
        ax += bf2f((ushort_t)(v[j] & 0xFFFF));
        ay += bf2f((ushort_t)(v[j] >> 16));
      }
    }
  }
  if (valid) {
    float bx = bias[2 * hl], by = bias[2 * hl + 1];
    ax = fmaf(di, ax, bx);
    ay = fmaf(di, ay, by);
    float2 o;
    o.x = ax;
    o.y = ay;
    *(float2*)(out + (size_t)node * DOUT + 2 * hl) = o;
  }
}

// ---------- launch ----------

extern "C" void kernel_launch(void* const* d_in, const int* in_sizes, int n_in,
                              void* d_out, int out_size, void* d_ws, size_t ws_size,
                              hipStream_t stream) {
  const float* x  = (const float*)d_in[0];
  const float* W1 = (const float*)d_in[1];
  const float* b1 = (const float*)d_in[2];
  const float* W2 = (const float*)d_in[3];
  const float* b2 = (const float*)d_in[4];
  const float* W3 = (const float*)d_in[5];
  const float* b3 = (const float*)d_in[6];
  const int* ei   = (const int*)d_in[7];  // harness delivers integers as int32

  int n = in_sizes[0] / DIN;
  int e = in_sizes[7] / 2;
  const int* src = ei;
  const int* dst = ei + e;

  char* ws = (char*)d_ws;
  size_t off = 0;
  auto alloc = [&](size_t bytes) -> void* {
    off = (off + 255) & ~(size_t)255;
    void* p = ws + off;
    off += bytes;
    return p;
  };
  int nbuckets = (n + 63) >> BSH;          // <= MAXB for n <= 65536
  int nbin = (e + EPB - 1) / EPB;

  int*      bucket_total = (int*)alloc((size_t)MAXB * 4);
  int*      bucket_base  = (int*)alloc((size_t)(MAXB + 1) * 4);
  int*      block_base   = (int*)alloc((size_t)nbin * nbuckets * 4);
  uint_t*   binned       = (uint_t*)alloc((size_t)e * 4);
  int*      deg          = (int*)alloc((size_t)n * 4);
  float*    dinv         = (float*)alloc((size_t)n * 4);
  int*      row_start    = (int*)alloc((size_t)n * 4);
  int*      col          = (int*)alloc((size_t)e * 4);
  ushort_t* Ta           = (ushort_t*)alloc((size_t)n * HID * 2);  // bf16 rows
  ushort_t* Tb           = (ushort_t*)alloc((size_t)n * HID * 2);  // bf16 rows
  ushort_t* W1hi         = (ushort_t*)alloc((size_t)DIN * HID * 2);
  ushort_t* W1lo         = (ushort_t*)alloc((size_t)DIN * HID * 2);
  ushort_t* W2hi         = (ushort_t*)alloc((size_t)HID * HID * 2);
  ushort_t* W2lo         = (ushort_t*)alloc((size_t)HID * HID * 2);
  ushort_t* W3hi         = (ushort_t*)alloc((size_t)HID * DOUT * 2);
  ushort_t* W3lo         = (ushort_t*)alloc((size_t)HID * DOUT * 2);
  (void)ws_size;

  int gemm_blocks = (n + 63) / 64;
  int sg_blocks = (n + 15) / 16;            // fused spmm_gemm: 16 nodes/block
  int nwaves = (n + 1) / 2;                 // 2 nodes per wave (final spmm)
  int spmm_blocks = (nwaves + 3) / 4;       // 4 waves per block
  constexpr int WPREP_TOTAL = DIN * HID + HID * HID + HID * DOUT;  // 57344
  int wblocks = (WPREP_TOTAL + 255) / 256;  // 224
  int iblocks = MAXB / 256;                 // 4

  initprep_kernel<<<iblocks + wblocks, 256, 0, stream>>>(
      bucket_total, iblocks,
      W1, W1hi, W1lo, W2, W2hi, W2lo, W3, W3hi, W3lo);
  bin_kernel<<<nbin, 256, 0, stream>>>(dst, e, nbuckets, bucket_total, block_base);
  scan_buckets_kernel<<<1, 256, 0, stream>>>(bucket_total, bucket_base, nbuckets);
  fusedA2_kernel<<<gemm_blocks + nbin, 256, 0, stream>>>(
      x, W1hi, W1lo, Ta, n, gemm_blocks,
      src, dst, bucket_base, block_base, binned, e, nbuckets);
  csr_kernel<<<nbuckets, 256, 0, stream>>>(binned, bucket_base, n, row_start,
                                           deg, dinv, col, Ta);

  // layer 1 agg + layer 2 GEMM (fused): Ta (pre-scaled bf16) -> Tb (scaled bf16)
  spmm_gemm_kernel<HID><<<sg_blocks, 512, 0, stream>>>(
      Ta, row_start, deg, col, dinv, b1, W2hi, W2lo, Tb, n);
  // layer 2 agg + layer 3 GEMM (fused): Tb -> Ta (n x 64, scaled bf16)
  spmm_gemm_kernel<DOUT><<<sg_blocks, 512, 0, stream>>>(
      Tb, row_start, deg, col, dinv, b2, W3hi, W3lo, Ta, n);
  // layer 3 agg (final): Ta -> out (fp32) + b3
  spmm64_kernel<<<spmm_blocks, 256, 0, stream>>>(
      Ta, row_start, deg, col, dinv, b3, (float*)d_out, n);
}